// Round 8
// baseline (1230.761 us; speedup 1.0000x reference)
//
#include <hip/hip_runtime.h>

typedef __attribute__((ext_vector_type(8))) short short8;
typedef __attribute__((ext_vector_type(4))) float f32x4;
typedef unsigned short u16;
typedef unsigned int u32;
typedef unsigned long long u64;

#define T_LEN 256
#define STEP_U16 32768          // one step's fragment set: 16kt*4nt*512 u16 = 64KB
#define CHUNK_U16 512

// workspace layout (bytes)
#define OFF_X0 0u
#define SZ_X0 (256u * 65536u)   // x0 fragments [t][kt][nt][lane][8] bf16, 16MB
#define OFF_Y0 (OFF_X0 + SZ_X0)
#define SZ_Y0 SZ_X0             // y (o-gate) fragments, 16MB
#define OFF_HD (OFF_Y0 + SZ_Y0)
#define SZ_HD (4u * 65536u)     // h ring: [layer][slot] 64KB each
#define OFF_POOL (OFF_HD + SZ_HD)
#define SZ_POOL (512u * 64u * 4u)
#define OFF_HFLG (OFF_POOL + SZ_POOL)
#define SZ_HFLG (4u * 128u)     // [group(layer,sb)]: 32 packed u32 flags (1 line)
#define OFF_YFLG (OFF_HFLG + SZ_HFLG)
#define SZ_YFLG (2u * 128u)     // [sb]: 32 packed u32 flags

__device__ __forceinline__ u16 f2bf(float x) {
  unsigned u = __builtin_bit_cast(unsigned, x);
  return (u16)((u + 0x7fffu + ((u >> 16) & 1u)) >> 16);
}
__device__ __forceinline__ float sigf(float x) { return 1.f / (1.f + __expf(-x)); }
__device__ __forceinline__ float tanhfast(float x) {
  float e = __expf(2.f * x);
  return 1.f - 2.f / (e + 1.f);
}

// LLC-coherent 16B load as 2x relaxed agent-scope 64-bit atomic loads (sc1).
__device__ __forceinline__ short8 ld16_llc(const u16* p) {
  const u64* q = (const u64*)p;
  u64 lo = __hip_atomic_load(q + 0, __ATOMIC_RELAXED, __HIP_MEMORY_SCOPE_AGENT);
  u64 hi = __hip_atomic_load(q + 1, __ATOMIC_RELAXED, __HIP_MEMORY_SCOPE_AGENT);
  union { u64 v[2]; short8 s; } u;
  u.v[0] = lo; u.v[1] = hi;
  return u.s;
}
__device__ __forceinline__ void st2_llc(u16* p, u16 v) {
  __hip_atomic_store(p, v, __ATOMIC_RELAXED, __HIP_MEMORY_SCOPE_AGENT);
}

__device__ __forceinline__ short8 cvt8(const float* src) {
  float4 lo = *(const float4*)src;
  float4 hi = *(const float4*)(src + 4);
  short8 fr;
  fr[0] = (short)f2bf(lo.x); fr[1] = (short)f2bf(lo.y);
  fr[2] = (short)f2bf(lo.z); fr[3] = (short)f2bf(lo.w);
  fr[4] = (short)f2bf(hi.x); fr[5] = (short)f2bf(hi.y);
  fr[6] = (short)f2bf(hi.z); fr[7] = (short)f2bf(hi.w);
  return fr;
}

// poll 32 packed flags (one 128B span; lane i reads dword i&31)
__device__ __forceinline__ void pollpk(const u32* base, int lane, u32 tgt, bool slp) {
  const u32* pf = base + (lane & 31);
  for (;;) {
    u32 v = __hip_atomic_load(pf, __ATOMIC_RELAXED, __HIP_MEMORY_SCOPE_AGENT);
    if (__all((int)(v >= tgt))) break;
    if (slp) __builtin_amdgcn_s_sleep(1);
  }
  asm volatile("" ::: "memory");
}

// ---- embedding gather into MFMA-B fragment layout (bf16) ----
__global__ void gather_x0(const int* __restrict__ in_t, const float* __restrict__ emb,
                          u16* __restrict__ x0) {
  int gid = blockIdx.x * 256 + threadIdx.x;
  int c = gid >> 6, lane = gid & 63;
  int t = c >> 6, rem = c & 63;
  int kt = rem >> 2, nt = rem & 3;
  int b = nt * 16 + (lane & 15);
  int k0 = kt * 32 + ((lane >> 4) * 8);
  int row = in_t[b * T_LEN + t];
  *(short8*)(x0 + (size_t)c * CHUNK_U16 + lane * 8) =
      cvt8(emb + (size_t)row * 512 + k0);
}

// ---- persistent recurrent kernel ----
// 128 blocks x 256 threads. bid: g=bid&3 (layer=g>>1, sb=g&1), u=bid>>2 (0..31).
// Unit: h-indices [16u,16u+16) (64 gate-rows, m = 4*h_local+gate) x samples
// [32sb,32sb+32). Wave w: K-slice [256w,256w+256): w<2 x-side (Wx), w>=2 h-side (Wh).
__global__ __launch_bounds__(256, 1) void lstm_persist(
    const float* __restrict__ wx, const float* __restrict__ bx,
    const float* __restrict__ wh, const float* __restrict__ bh,
    const u16* __restrict__ x0, u16* __restrict__ y0,
    u16* __restrict__ hd, float* __restrict__ pool,
    u32* __restrict__ hflg, u32* __restrict__ yflg) {
  __shared__ float part[4][64][34];   // [wave][gate-row][sample], stride 34

  const int tid = threadIdx.x;
  const int w = tid >> 6, lane = tid & 63;
  const int q = lane >> 4, col = lane & 15;
  const int bid = blockIdx.x;
  const int g = bid & 3;
  const int layer = g >> 1, sb = g & 1;
  const int u = bid >> 2;          // 0..31
  const int side = w >> 1;         // 0: x (Wx), 1: h (Wh)

  // ---- weight fragments: 4 m-tiles x 8 k-steps = 128 VGPRs ----
  short8 afrag[4][8];
  {
    const int gt = col & 3;
    const int kb = (w & 1) * 256 + q * 8;   // k within this side's 512
#pragma unroll
    for (int mt = 0; mt < 4; ++mt) {
      const int h_l = u * 16 + mt * 4 + (col >> 2);
      const float* wrow = (side == 0 ? wx : wh) +
                          ((size_t)(layer * 4 + gt) * 512 + h_l) * 512;
#pragma unroll
      for (int ks = 0; ks < 8; ++ks)
        afrag[mt][ks] = cvt8(wrow + kb + ks * 32);
    }
  }
  // epilogue ownership: pairs (hl,bl) and (hl+8,bl)
  const int hl = tid >> 5, bl = tid & 31;
  float bias0[4], bias1[4];
#pragma unroll
  for (int r = 0; r < 4; ++r) {
    const int h0 = u * 16 + hl, h1 = u * 16 + 8 + hl;
    bias0[r] = bx[(layer * 4 + r) * 512 + h0] + bh[(layer * 4 + r) * 512 + h0];
    bias1[r] = bx[(layer * 4 + r) * 512 + h1] + bh[(layer * 4 + r) * 512 + h1];
  }
  // epilogue store addresses (fragment layout) for the 2 owned h-values
  const int hg0 = u * 16 + hl, hg1 = u * 16 + 8 + hl;
  const size_t off0 = ((size_t)((hg0 >> 5) * 4 + sb * 2 + (bl >> 4)) * 64 +
                       (bl & 15) + 16 * ((hg0 >> 3) & 3)) * 8 + (hg0 & 7);
  const size_t off1 = ((size_t)((hg1 >> 5) * 4 + sb * 2 + (bl >> 4)) * 64 +
                       (bl & 15) + 16 * ((hg1 >> 3) & 3)) * 8 + (hg1 & 7);

  const u16* xl = (layer == 0) ? x0 : y0;
  u16* hdl = hd + (size_t)layer * 2 * STEP_U16;
  u32* hf_own = hflg + (size_t)g * 32 + u;
  const u32* hf_grp = hflg + (size_t)g * 32;
  u32* yf_own = yflg + (size_t)sb * 32 + u;
  const u32* yf_grp = yflg + (size_t)sb * 32;

  float2 cst = {0.f, 0.f};
  float2 opool = {0.f, 0.f};

  for (int t = 0; t < T_LEN; ++t) {
    // ---- compute phase (per-wave) ----
    {
      const u16* src;
      bool plain;
      if (side == 0) {
        src = xl + (size_t)t * STEP_U16;
        plain = (layer == 0);
        if (layer == 1) pollpk(yf_grp, lane, (u32)(t + 1), true);
      } else {
        src = hdl + (size_t)(t & 1) * STEP_U16;
        plain = false;
        pollpk(hf_grp, lane, (u32)t, false);   // critical path: tight poll
      }
      f32x4 acc[4][2] = {};
#pragma unroll
      for (int ks = 0; ks < 8; ++ks) {
        const int ktl = (w & 1) * 8 + ks;   // local kt within step buffer
        const u16* p = src + ((size_t)(ktl * 4 + 2 * sb) * 64 + lane) * 8;
        short8 f0, f1;
        if (plain) {
          f0 = *(const short8*)p;
          f1 = *(const short8*)(p + CHUNK_U16);
        } else {
          f0 = ld16_llc(p);
          f1 = ld16_llc(p + CHUNK_U16);
        }
#pragma unroll
        for (int mt = 0; mt < 4; ++mt) {
          acc[mt][0] = __builtin_amdgcn_mfma_f32_16x16x32_bf16(afrag[mt][ks], f0,
                                                               acc[mt][0], 0, 0, 0);
          acc[mt][1] = __builtin_amdgcn_mfma_f32_16x16x32_bf16(afrag[mt][ks], f1,
                                                               acc[mt][1], 0, 0, 0);
        }
      }
      // partials -> LDS (C/D layout: col=lane&15, row=4*(lane>>4)+r)
#pragma unroll
      for (int mt = 0; mt < 4; ++mt)
#pragma unroll
        for (int ntl = 0; ntl < 2; ++ntl)
#pragma unroll
          for (int r = 0; r < 4; ++r)
            part[w][mt * 16 + q * 4 + r][ntl * 16 + col] = acc[mt][ntl][r];
    }
    __syncthreads();   // barrier 1: partials ready

    // ---- epilogue: 4-way reduce + gates + DIRECT sc1 stores ----
    u16* hdst = hdl + (size_t)((t + 1) & 1) * STEP_U16;
    u16* ydst = y0 + (size_t)t * STEP_U16;
#pragma unroll
    for (int P = 0; P < 2; ++P) {
      const int hloc = hl + P * 8;
      float v[4];
#pragma unroll
      for (int gt = 0; gt < 4; ++gt) {
        const int row = hloc * 4 + gt;
        v[gt] = part[0][row][bl] + part[1][row][bl] + part[2][row][bl] +
                part[3][row][bl] + (P ? bias1[gt] : bias0[gt]);
      }
      const float ig = sigf(v[0]);
      const float fg = sigf(v[1]);
      const float gg = tanhfast(v[2]);
      const float og = sigf(v[3]);
      const float cp = P ? cst.y : cst.x;
      const float cn = fg * cp + ig * gg;   // c input = prev h_new (unpack bug)
      const float hn = og * tanhfast(cn);
      if (P) cst.y = hn; else cst.x = hn;
      const size_t off = P ? off1 : off0;
      st2_llc(hdst + off, f2bf(cn));        // c_new -> next h-input (bug)
      if (layer == 0) {
        st2_llc(ydst + off, f2bf(og));      // o-gate -> L1 input sequence
      } else {
        if (P) opool.y += og; else opool.x += og;
      }
    }
    asm volatile("s_waitcnt vmcnt(0)" ::: "memory");  // own stores acked at LLC
    __syncthreads();   // barrier 2: all threads' stores done; part[] fully read

    // ---- packed flags (one dword per unit in the group's line) ----
    if (tid == 0)
      __hip_atomic_store(hf_own, (u32)(t + 1), __ATOMIC_RELAXED,
                         __HIP_MEMORY_SCOPE_AGENT);
    if (tid == 1 && layer == 0)
      __hip_atomic_store(yf_own, (u32)(t + 1), __ATOMIC_RELAXED,
                         __HIP_MEMORY_SCOPE_AGENT);
  }

  if (layer == 1) {
    pool[(size_t)(u * 16 + hl) * 64 + sb * 32 + bl] = opool.x;
    pool[(size_t)(u * 16 + 8 + hl) * 64 + sb * 32 + bl] = opool.y;
  }
}

// ---- final pooled @ wo.T + bo -> sigmoid ----
__global__ void finalize_k(const float* __restrict__ pool, const float* __restrict__ wo,
                           const float* __restrict__ bo, float* __restrict__ out) {
  const int b = threadIdx.x;
  float s = 0.f;
  for (int h = 0; h < 512; ++h) s += pool[h * 64 + b] * wo[h];
  out[b] = sigf(s * (1.f / 256.f) + bo[0]);
}

extern "C" void kernel_launch(void* const* d_in, const int* in_sizes, int n_in,
                              void* d_out, int out_size, void* d_ws, size_t ws_size,
                              hipStream_t stream) {
  const int* in_t = (const int*)d_in[0];
  const float* emb = (const float*)d_in[1];
  const float* wx = (const float*)d_in[2];
  const float* bx = (const float*)d_in[3];
  const float* wh = (const float*)d_in[4];
  const float* bh = (const float*)d_in[5];
  const float* wo = (const float*)d_in[6];
  const float* bo = (const float*)d_in[7];
  float* out = (float*)d_out;
  char* ws = (char*)d_ws;
  u16* x0 = (u16*)(ws + OFF_X0);
  u16* y0 = (u16*)(ws + OFF_Y0);
  u16* hd = (u16*)(ws + OFF_HD);
  float* pool = (float*)(ws + OFF_POOL);
  u32* hflg = (u32*)(ws + OFF_HFLG);
  u32* yflg = (u32*)(ws + OFF_YFLG);

  hipMemsetAsync(ws + OFF_HD, 0, SZ_HD, stream);                 // h(0) = 0
  hipMemsetAsync(ws + OFF_HFLG, 0, SZ_HFLG + SZ_YFLG, stream);   // step flags
  gather_x0<<<4096, 256, 0, stream>>>(in_t, emb, x0);
  lstm_persist<<<128, 256, 0, stream>>>(wx, bx, wh, bh, x0, y0, hd, pool,
                                        hflg, yflg);
  finalize_k<<<1, 64, 0, stream>>>(pool, wo, bo, out);
}